// Round 1
// baseline (337.444 us; speedup 1.0000x reference)
//
#include <hip/hip_runtime.h>

constexpr int B = 8, N = 1024, FIN = 128, FOUT = 64, H = 4;

// ---------------------------------------------------------------------------
// Kernel A: h_prime = einsum('bni,hio->bnho') stored transposed as (B,H,N,F),
//           ei/ej   = einsum('bnhf,hf->bnh')  stored as (B,H,N).
// Block = 16 rows of h staged in LDS; wave w handles head w; thread covers
// 4 rows (g+4k) x 4 f (f0..f0+3).
// ---------------------------------------------------------------------------
__global__ __launch_bounds__(256) void gat_prep(
    const float* __restrict__ h,     // (B,N,FIN)
    const float* __restrict__ W,     // (H,FIN,FOUT)
    const float* __restrict__ a,     // (H, 2*FOUT, 1)
    float* __restrict__ hp_t,        // (B,H,N,FOUT)
    float* __restrict__ ei_t,        // (B,H,N)
    float* __restrict__ ej_t)        // (B,H,N)
{
    __shared__ float h_lds[16][132];   // +4 pad: rows g,g+4,.. land on 2 banks (free)
    const int t  = threadIdx.x;
    const int blk = blockIdx.x;              // 0 .. B*N/16-1
    const int b  = blk / (N / 16);
    const int n0 = (blk % (N / 16)) * 16;

    // stage 16 rows x 128 floats (8 KB), float4, 2 iters/thread
    {
        const float* src = h + ((size_t)b * N + n0) * FIN;
        for (int v = t; v < 16 * FIN / 4; v += 256) {
            float4 x = reinterpret_cast<const float4*>(src)[v];
            int fl = v * 4;
            int r = fl >> 7;        // /128
            int c = fl & 127;
            *reinterpret_cast<float4*>(&h_lds[r][c]) = x;
        }
    }
    __syncthreads();

    const int hd   = t >> 6;          // head = wave
    const int lane = t & 63;
    const int g    = lane >> 4;       // row group 0..3
    const int f0   = (lane & 15) * 4; // f base

    float acc[4][4];
    #pragma unroll
    for (int k = 0; k < 4; ++k)
        #pragma unroll
        for (int j = 0; j < 4; ++j) acc[k][j] = 0.f;

    const float* Wp = W + (size_t)hd * FIN * FOUT + f0;
    #pragma unroll 2
    for (int i = 0; i < FIN; ++i) {
        float4 w = *reinterpret_cast<const float4*>(Wp + (size_t)i * FOUT);
        #pragma unroll
        for (int k = 0; k < 4; ++k) {
            float hv = h_lds[g + 4 * k][i];
            acc[k][0] = fmaf(hv, w.x, acc[k][0]);
            acc[k][1] = fmaf(hv, w.y, acc[k][1]);
            acc[k][2] = fmaf(hv, w.z, acc[k][2]);
            acc[k][3] = fmaf(hv, w.w, acc[k][3]);
        }
    }

    // store h_prime transposed (B,H,N,F)
    #pragma unroll
    for (int k = 0; k < 4; ++k) {
        int r = n0 + g + 4 * k;
        float4 v = make_float4(acc[k][0], acc[k][1], acc[k][2], acc[k][3]);
        *reinterpret_cast<float4*>(hp_t + (((size_t)b * H + hd) * N + r) * FOUT + f0) = v;
    }

    // ei/ej: dot with a1/a2 then reduce across the 16 f-lanes
    float4 a1 = *reinterpret_cast<const float4*>(a + (size_t)hd * 2 * FOUT + f0);
    float4 a2 = *reinterpret_cast<const float4*>(a + (size_t)hd * 2 * FOUT + FOUT + f0);
    #pragma unroll
    for (int k = 0; k < 4; ++k) {
        float e1 = acc[k][0] * a1.x + acc[k][1] * a1.y + acc[k][2] * a1.z + acc[k][3] * a1.w;
        float e2 = acc[k][0] * a2.x + acc[k][1] * a2.y + acc[k][2] * a2.z + acc[k][3] * a2.w;
        #pragma unroll
        for (int m = 1; m < 16; m <<= 1) {
            e1 += __shfl_xor(e1, m, 64);
            e2 += __shfl_xor(e2, m, 64);
        }
        if ((lane & 15) == 0) {
            int r = n0 + g + 4 * k;
            ei_t[((size_t)b * H + hd) * N + r] = e1;
            ej_t[((size_t)b * H + hd) * N + r] = e2;
        }
    }
}

// ---------------------------------------------------------------------------
// Kernel B: fused scores + softmax + PV.
// Block = (b, head, 16-row i-tile). Score stage writes UNNORMALIZED p=exp(e)
// (max-subtraction dropped: scores bounded ~|10|, fp32-safe; masked -> 0)
// into a 64KB LDS tile, XOR-swizzled per 16B group so PV's 4-distinct-row
// ds_read_b128 is bank-conflict-free. PV: thread = (row r, 4 f's), row-sum
// accumulated from the p4 registers already loaded; normalize at the end.
// ---------------------------------------------------------------------------
__global__ __launch_bounds__(256) void gat_attn(
    const float* __restrict__ hp_t,   // (B,H,N,FOUT)
    const float* __restrict__ ei_t,   // (B,H,N)
    const float* __restrict__ ej_t,   // (B,H,N)
    const float* __restrict__ bias,   // (N,N)
    const int*   __restrict__ adj,    // (N,N)
    float* __restrict__ out)          // (B,N,H*FOUT)
{
    __shared__ float p_lds[16 * 1024];   // exactly 64 KB
    const int t    = threadIdx.x;
    const int blk  = blockIdx.x;
    const int tile = blk % (N / 16);
    const int bh   = blk / (N / 16);    // b*H + head
    const int b    = bh >> 2;
    const int hd   = bh & 3;
    const int i0   = tile * 16;

    const float* ejrow = ej_t + (size_t)bh * N;
    const float* eirow = ei_t + (size_t)bh * N + i0;

    // ---- score stage: p[r][j] = adj ? exp(lrelu(ei+ej) + bias) : 0 ----
    for (int idx = t; idx < 16 * 1024; idx += 256) {
        int r = idx >> 10;
        int j = idx & 1023;
        float e = eirow[r] + ejrow[j];
        e = e > 0.f ? e : 0.2f * e;
        e += bias[(size_t)(i0 + r) * N + j];
        float p = (adj[(size_t)(i0 + r) * N + j] != 0) ? __expf(e) : 0.f;
        int q = (j >> 2) ^ (r & 7);                 // float4-granular swizzle
        p_lds[r * 1024 + q * 4 + (j & 3)] = p;
    }
    __syncthreads();

    // ---- PV: out[r][f] = (1/sum_j p) * sum_j p[r][j] * hp[j][f] ----
    const int r  = t >> 4;            // one row per thread
    const int f0 = (t & 15) * 4;      // 4 f's per thread
    const float* hpb = hp_t + ((size_t)bh * N) * FOUT;

    float acc0 = 0.f, acc1 = 0.f, acc2 = 0.f, acc3 = 0.f, psum = 0.f;
    #pragma unroll 2
    for (int j = 0; j < N; j += 4) {
        int q = (j >> 2) ^ (r & 7);
        float4 p4 = *reinterpret_cast<const float4*>(&p_lds[r * 1024 + q * 4]);
        const float* hp0 = hpb + (size_t)j * FOUT + f0;
        float4 v0 = *reinterpret_cast<const float4*>(hp0);
        float4 v1 = *reinterpret_cast<const float4*>(hp0 + FOUT);
        float4 v2 = *reinterpret_cast<const float4*>(hp0 + 2 * FOUT);
        float4 v3 = *reinterpret_cast<const float4*>(hp0 + 3 * FOUT);
        acc0 = fmaf(p4.x, v0.x, acc0); acc1 = fmaf(p4.x, v0.y, acc1);
        acc2 = fmaf(p4.x, v0.z, acc2); acc3 = fmaf(p4.x, v0.w, acc3);
        acc0 = fmaf(p4.y, v1.x, acc0); acc1 = fmaf(p4.y, v1.y, acc1);
        acc2 = fmaf(p4.y, v1.z, acc2); acc3 = fmaf(p4.y, v1.w, acc3);
        acc0 = fmaf(p4.z, v2.x, acc0); acc1 = fmaf(p4.z, v2.y, acc1);
        acc2 = fmaf(p4.z, v2.z, acc2); acc3 = fmaf(p4.z, v2.w, acc3);
        acc0 = fmaf(p4.w, v3.x, acc0); acc1 = fmaf(p4.w, v3.y, acc1);
        acc2 = fmaf(p4.w, v3.z, acc2); acc3 = fmaf(p4.w, v3.w, acc3);
        psum += (p4.x + p4.y) + (p4.z + p4.w);
    }

    float inv = 1.0f / psum;
    float4 o = make_float4(acc0 * inv, acc1 * inv, acc2 * inv, acc3 * inv);
    *reinterpret_cast<float4*>(
        out + (((size_t)b * N + i0 + r) * H + hd) * FOUT + f0) = o;
}

extern "C" void kernel_launch(void* const* d_in, const int* in_sizes, int n_in,
                              void* d_out, int out_size, void* d_ws, size_t ws_size,
                              hipStream_t stream) {
    const float* h    = (const float*)d_in[0];
    const int*   adj  = (const int*)  d_in[1];
    const float* bias = (const float*)d_in[2];
    const float* W    = (const float*)d_in[3];
    const float* a    = (const float*)d_in[4];
    float* out = (float*)d_out;

    char* ws = (char*)d_ws;
    float* hp_t = (float*)ws;                                  // 8 MB
    float* ei_t = (float*)(ws + (size_t)B * H * N * FOUT * 4); // 128 KB
    float* ej_t = ei_t + (size_t)B * H * N;                    // 128 KB

    gat_prep<<<B * N / 16, 256, 0, stream>>>(h, W, a, hp_t, ei_t, ej_t);
    gat_attn<<<B * H * (N / 16), 256, 0, stream>>>(hp_t, ei_t, ej_t, bias, adj, out);
}

// Round 2
// 114.742 us; speedup vs baseline: 2.9409x; 2.9409x over previous
//
#include <hip/hip_runtime.h>

constexpr int B = 8, N = 1024, FIN = 128, FOUT = 64, H = 4;

typedef __attribute__((ext_vector_type(8))) short short8;
typedef __attribute__((ext_vector_type(4))) short short4v;
typedef __attribute__((ext_vector_type(4))) float f32x4;

// f32 -> bf16 round-to-nearest-even
static __device__ inline unsigned short f2bf(float x) {
    union { float f; unsigned u; } v; v.f = x;
    unsigned r = v.u + 0x7fff + ((v.u >> 16) & 1);
    return (unsigned short)(r >> 16);
}

// ---------------------------------------------------------------------------
// mb[i][j] = adj ? bias : -1e30   (fused mask+bias: exp(-1e30)=0, so softmax
// needs no max-subtraction and masked lanes cost nothing downstream)
// ---------------------------------------------------------------------------
__global__ __launch_bounds__(256) void mb_prep(
    const int* __restrict__ adj, const float* __restrict__ bias,
    float* __restrict__ mb)
{
    int idx = blockIdx.x * 256 + threadIdx.x;   // over N*N/4
    int4   a4 = reinterpret_cast<const int4*>(adj)[idx];
    float4 b4 = reinterpret_cast<const float4*>(bias)[idx];
    float4 o;
    o.x = a4.x ? b4.x : -1e30f;
    o.y = a4.y ? b4.y : -1e30f;
    o.z = a4.z ? b4.z : -1e30f;
    o.w = a4.w ? b4.w : -1e30f;
    reinterpret_cast<float4*>(mb)[idx] = o;
}

// ---------------------------------------------------------------------------
// Kernel A: h_prime GEMM. Outputs:
//   hpT  (B,H,FOUT=64,N) bf16  -- f-major so PV B-fragments are contiguous 16B
//   ei/ej (B,H,N) f32
// Block = 16 rows; wave = head; thread = 4 consecutive rows (4g+k) x 4 f.
// ---------------------------------------------------------------------------
__global__ __launch_bounds__(256) void gat_prep(
    const float* __restrict__ h,      // (B,N,FIN)
    const float* __restrict__ W,      // (H,FIN,FOUT)
    const float* __restrict__ a,      // (H,2*FOUT,1)
    unsigned short* __restrict__ hpT, // (B,H,64,N) bf16
    float* __restrict__ ei_t,         // (B,H,N)
    float* __restrict__ ej_t)         // (B,H,N)
{
    __shared__ float h_lds[16][132];
    const int t   = threadIdx.x;
    const int blk = blockIdx.x;            // 0 .. B*N/16-1
    const int b   = blk / (N / 16);
    const int n0  = (blk % (N / 16)) * 16;

    {
        const float* src = h + ((size_t)b * N + n0) * FIN;
        for (int v = t; v < 16 * FIN / 4; v += 256) {
            float4 x = reinterpret_cast<const float4*>(src)[v];
            int fl = v * 4;
            *reinterpret_cast<float4*>(&h_lds[fl >> 7][fl & 127]) = x;
        }
    }
    __syncthreads();

    const int hd   = t >> 6;
    const int lane = t & 63;
    const int g    = lane >> 4;
    const int f0   = (lane & 15) * 4;

    float acc[4][4];                        // acc[k][jj]: row n0+4g+k, f f0+jj
    #pragma unroll
    for (int k = 0; k < 4; ++k)
        #pragma unroll
        for (int j = 0; j < 4; ++j) acc[k][j] = 0.f;

    const float* Wp = W + (size_t)hd * FIN * FOUT + f0;
    #pragma unroll 2
    for (int i = 0; i < FIN; ++i) {
        float4 w = *reinterpret_cast<const float4*>(Wp + (size_t)i * FOUT);
        #pragma unroll
        for (int k = 0; k < 4; ++k) {
            float hv = h_lds[4 * g + k][i];
            acc[k][0] = fmaf(hv, w.x, acc[k][0]);
            acc[k][1] = fmaf(hv, w.y, acc[k][1]);
            acc[k][2] = fmaf(hv, w.z, acc[k][2]);
            acc[k][3] = fmaf(hv, w.w, acc[k][3]);
        }
    }

    const int bh = b * H + hd;
    // hpT store: for each f (f0+jj), 4 consecutive n -> one 8B bf16x4 store
    #pragma unroll
    for (int jj = 0; jj < 4; ++jj) {
        short4v v4;
        v4[0] = (short)f2bf(acc[0][jj]);
        v4[1] = (short)f2bf(acc[1][jj]);
        v4[2] = (short)f2bf(acc[2][jj]);
        v4[3] = (short)f2bf(acc[3][jj]);
        *reinterpret_cast<short4v*>(
            hpT + ((size_t)bh * 64 + f0 + jj) * N + n0 + 4 * g) = v4;
    }

    float4 a1 = *reinterpret_cast<const float4*>(a + (size_t)hd * 2 * FOUT + f0);
    float4 a2 = *reinterpret_cast<const float4*>(a + (size_t)hd * 2 * FOUT + FOUT + f0);
    #pragma unroll
    for (int k = 0; k < 4; ++k) {
        float e1 = acc[k][0] * a1.x + acc[k][1] * a1.y + acc[k][2] * a1.z + acc[k][3] * a1.w;
        float e2 = acc[k][0] * a2.x + acc[k][1] * a2.y + acc[k][2] * a2.z + acc[k][3] * a2.w;
        #pragma unroll
        for (int m = 1; m < 16; m <<= 1) {
            e1 += __shfl_xor(e1, m, 64);
            e2 += __shfl_xor(e2, m, 64);
        }
        if ((lane & 15) == 0) {
            int r = n0 + 4 * g + k;
            ei_t[(size_t)bh * N + r] = e1;
            ej_t[(size_t)bh * N + r] = e2;
        }
    }
}

// ---------------------------------------------------------------------------
// Kernel B: fully fused flash-style scores+softmax+PV on MFMA. No LDS, no
// barriers. Block = 4 waves = (b,h, 32 i-rows); wave ft owns f-tile ft.
// Per K-chunk (32 j): each lane computes its 16 A-fragment scores directly
// (i = l&15 [+16], j = j0+8*(l>>4)+e) -- A and B use the same k-bijection so
// the MFMA contraction is layout-robust. Row sums accumulate in f32 regs;
// normalization in the epilogue via shfl.
// ---------------------------------------------------------------------------
__global__ __launch_bounds__(256) void gat_attn(
    const unsigned short* __restrict__ hpT, // (B,H,64,N) bf16
    const float* __restrict__ ei_t,         // (B,H,N)
    const float* __restrict__ ej_t,         // (B,H,N)
    const float* __restrict__ mb,           // (N,N) masked bias
    float* __restrict__ out)                // (B,N,H*FOUT)
{
    const int t    = threadIdx.x;
    const int blk  = blockIdx.x;
    const int bh   = blk >> 5;              // b*H + h
    const int i0   = (blk & 31) * 32;
    const int ft   = t >> 6;                // wave = f-tile
    const int lane = t & 63;
    const int li   = lane & 15;
    const int kg   = lane >> 4;

    const float* ejrow = ej_t + (size_t)bh * N;
    const float  ei0   = ei_t[(size_t)bh * N + i0 + li];
    const float  ei1   = ei_t[(size_t)bh * N + i0 + 16 + li];
    const float* mb0   = mb + (size_t)(i0 + li) * N;
    const float* mb1   = mb0 + 16 * N;
    const unsigned short* bp = hpT + ((size_t)bh * 64 + ft * 16 + li) * N;

    f32x4 c0 = {0.f, 0.f, 0.f, 0.f};
    f32x4 c1 = {0.f, 0.f, 0.f, 0.f};
    float ps0 = 0.f, ps1 = 0.f;

    for (int j0 = 0; j0 < N; j0 += 32) {
        const int jb = j0 + 8 * kg;
        float4 ejA = *reinterpret_cast<const float4*>(ejrow + jb);
        float4 ejB = *reinterpret_cast<const float4*>(ejrow + jb + 4);
        short8 bfr = *reinterpret_cast<const short8*>(bp + jb);

        float4 mA0 = *reinterpret_cast<const float4*>(mb0 + jb);
        float4 mB0 = *reinterpret_cast<const float4*>(mb0 + jb + 4);
        float4 mA1 = *reinterpret_cast<const float4*>(mb1 + jb);
        float4 mB1 = *reinterpret_cast<const float4*>(mb1 + jb + 4);

        short8 a0, a1;
        #define SC(EI, EJ, MB, PS, DST, IDX) {                     \
            float e_ = (EI) + (EJ);                                \
            e_ = fmaxf(e_, 0.2f * e_) + (MB);                      \
            float p_ = __expf(e_);                                 \
            PS += p_;                                              \
            DST[IDX] = (short)f2bf(p_); }
        SC(ei0, ejA.x, mA0.x, ps0, a0, 0)
        SC(ei0, ejA.y, mA0.y, ps0, a0, 1)
        SC(ei0, ejA.z, mA0.z, ps0, a0, 2)
        SC(ei0, ejA.w, mA0.w, ps0, a0, 3)
        SC(ei0, ejB.x, mB0.x, ps0, a0, 4)
        SC(ei0, ejB.y, mB0.y, ps0, a0, 5)
        SC(ei0, ejB.z, mB0.z, ps0, a0, 6)
        SC(ei0, ejB.w, mB0.w, ps0, a0, 7)
        SC(ei1, ejA.x, mA1.x, ps1, a1, 0)
        SC(ei1, ejA.y, mA1.y, ps1, a1, 1)
        SC(ei1, ejA.z, mA1.z, ps1, a1, 2)
        SC(ei1, ejA.w, mA1.w, ps1, a1, 3)
        SC(ei1, ejB.x, mB1.x, ps1, a1, 4)
        SC(ei1, ejB.y, mB1.y, ps1, a1, 5)
        SC(ei1, ejB.z, mB1.z, ps1, a1, 6)
        SC(ei1, ejB.w, mB1.w, ps1, a1, 7)
        #undef SC

        c0 = __builtin_amdgcn_mfma_f32_16x16x32_bf16(a0, bfr, c0, 0, 0, 0);
        c1 = __builtin_amdgcn_mfma_f32_16x16x32_bf16(a1, bfr, c1, 0, 0, 0);
    }

    // full row sums: reduce across the 4 k-groups
    ps0 += __shfl_xor(ps0, 16, 64); ps0 += __shfl_xor(ps0, 32, 64);
    ps1 += __shfl_xor(ps1, 16, 64); ps1 += __shfl_xor(ps1, 32, 64);

    const int b  = bh >> 2;
    const int hd = bh & 3;
    float* obase = out + ((size_t)b * N + i0) * (H * FOUT) + hd * FOUT + ft * 16 + li;
    #pragma unroll
    for (int r = 0; r < 4; ++r) {
        int row = 4 * kg + r;                        // C layout: col=l&15, row=(l>>4)*4+reg
        float inv0 = 1.0f / __shfl(ps0, row, 64);
        float inv1 = 1.0f / __shfl(ps1, row, 64);
        obase[(size_t)row * (H * FOUT)]        = c0[r] * inv0;
        obase[(size_t)(16 + row) * (H * FOUT)] = c1[r] * inv1;
    }
}

extern "C" void kernel_launch(void* const* d_in, const int* in_sizes, int n_in,
                              void* d_out, int out_size, void* d_ws, size_t ws_size,
                              hipStream_t stream) {
    const float* h    = (const float*)d_in[0];
    const int*   adj  = (const int*)  d_in[1];
    const float* bias = (const float*)d_in[2];
    const float* W    = (const float*)d_in[3];
    const float* a    = (const float*)d_in[4];
    float* out = (float*)d_out;

    char* ws = (char*)d_ws;
    unsigned short* hpT = (unsigned short*)ws;                       // 4 MB
    float* mb   = (float*)(ws + (size_t)B * H * 64 * N * 2);         // 4 MB
    float* ei_t = (float*)(ws + (size_t)B * H * 64 * N * 2 + (size_t)N * N * 4);
    float* ej_t = ei_t + (size_t)B * H * N;

    mb_prep<<<N * N / 4 / 256, 256, 0, stream>>>(adj, bias, mb);
    gat_prep<<<B * N / 16, 256, 0, stream>>>(h, W, a, hpT, ei_t, ej_t);
    gat_attn<<<B * H * (N / 32), 256, 0, stream>>>(hpT, ei_t, ej_t, mb, out);
}

// Round 4
// 74.119 us; speedup vs baseline: 4.5527x; 1.5481x over previous
//
#include <hip/hip_runtime.h>

constexpr int B = 8, N = 1024, FIN = 128, FOUT = 64, H = 4;

typedef __attribute__((ext_vector_type(8))) short short8;
typedef __attribute__((ext_vector_type(4))) short short4v;
typedef __attribute__((ext_vector_type(4))) float f32x4;

// f32 -> bf16 round-to-nearest-even
static __device__ inline unsigned short f2bf(float x) {
    union { float f; unsigned u; } v; v.f = x;
    unsigned r = v.u + 0x7fff + ((v.u >> 16) & 1);
    return (unsigned short)(r >> 16);
}

// ---------------------------------------------------------------------------
// mb[i][j] = adj ? bias : -1e30   (exp(-1e30)=0 -> no max-subtraction needed)
// ---------------------------------------------------------------------------
__global__ __launch_bounds__(256) void mb_prep(
    const int* __restrict__ adj, const float* __restrict__ bias,
    float* __restrict__ mb)
{
    int idx = blockIdx.x * 256 + threadIdx.x;   // over N*N/4
    int4   a4 = reinterpret_cast<const int4*>(adj)[idx];
    float4 b4 = reinterpret_cast<const float4*>(bias)[idx];
    float4 o;
    o.x = a4.x ? b4.x : -1e30f;
    o.y = a4.y ? b4.y : -1e30f;
    o.z = a4.z ? b4.z : -1e30f;
    o.w = a4.w ? b4.w : -1e30f;
    reinterpret_cast<float4*>(mb)[idx] = o;
}

// ---------------------------------------------------------------------------
// Kernel A: h_prime GEMM + ei/ej. Block = 8 rows; wave = head; within a wave
// lanes split K in halves (kh = lane>>5), combined via shfl_xor(32).
// Outputs hpT (B,H,64,N) bf16 f-major, ei/ej (B,H,N) f32.
// Grid = B*N/8 = 1024 blocks (4/CU).
// ---------------------------------------------------------------------------
__global__ __launch_bounds__(256) void gat_prep(
    const float* __restrict__ h,      // (B,N,FIN)
    const float* __restrict__ W,      // (H,FIN,FOUT)
    const float* __restrict__ a,      // (H,2*FOUT,1)
    unsigned short* __restrict__ hpT, // (B,H,64,N) bf16
    float* __restrict__ ei_t,         // (B,H,N)
    float* __restrict__ ej_t)         // (B,H,N)
{
    __shared__ float h_lds[8][132];
    const int t   = threadIdx.x;
    const int blk = blockIdx.x;            // 0 .. B*N/8-1
    const int b   = blk >> 7;              // / (N/8)
    const int n0  = (blk & 127) * 8;

    {   // stage 8 x 128 floats: exactly one float4 per thread
        const float* src = h + ((size_t)b * N + n0) * FIN;
        float4 x = reinterpret_cast<const float4*>(src)[t];
        int fl = t * 4;
        *reinterpret_cast<float4*>(&h_lds[fl >> 7][fl & 127]) = x;
    }
    __syncthreads();

    const int hd   = t >> 6;
    const int lane = t & 63;
    const int f0   = (lane & 15) * 4;
    const int g    = (lane >> 4) & 1;      // rows 4g .. 4g+3
    const int kh   = lane >> 5;            // K half

    float acc[4][4];
    #pragma unroll
    for (int k = 0; k < 4; ++k)
        #pragma unroll
        for (int j = 0; j < 4; ++j) acc[k][j] = 0.f;

    const float* Wp = W + (size_t)hd * FIN * FOUT + (size_t)kh * 64 * FOUT + f0;
    #pragma unroll 4
    for (int i = 0; i < 64; ++i) {
        float4 w4 = *reinterpret_cast<const float4*>(Wp + (size_t)i * FOUT);
        #pragma unroll
        for (int k = 0; k < 4; ++k) {
            float hv = h_lds[4 * g + k][kh * 64 + i];
            acc[k][0] = fmaf(hv, w4.x, acc[k][0]);
            acc[k][1] = fmaf(hv, w4.y, acc[k][1]);
            acc[k][2] = fmaf(hv, w4.z, acc[k][2]);
            acc[k][3] = fmaf(hv, w4.w, acc[k][3]);
        }
    }

    // combine the two K halves (both lanes of each pair get the full sum)
    #pragma unroll
    for (int k = 0; k < 4; ++k)
        #pragma unroll
        for (int j = 0; j < 4; ++j)
            acc[k][j] += __shfl_xor(acc[k][j], 32, 64);

    const int bh = b * H + hd;
    if (kh == 0) {
        #pragma unroll
        for (int jj = 0; jj < 4; ++jj) {
            short4v v4;
            v4[0] = (short)f2bf(acc[0][jj]);
            v4[1] = (short)f2bf(acc[1][jj]);
            v4[2] = (short)f2bf(acc[2][jj]);
            v4[3] = (short)f2bf(acc[3][jj]);
            *reinterpret_cast<short4v*>(
                hpT + ((size_t)bh * 64 + f0 + jj) * N + n0 + 4 * g) = v4;
        }
    }

    float4 a1 = *reinterpret_cast<const float4*>(a + (size_t)hd * 2 * FOUT + f0);
    float4 a2 = *reinterpret_cast<const float4*>(a + (size_t)hd * 2 * FOUT + FOUT + f0);
    #pragma unroll
    for (int k = 0; k < 4; ++k) {
        float e1 = acc[k][0] * a1.x + acc[k][1] * a1.y + acc[k][2] * a1.z + acc[k][3] * a1.w;
        float e2 = acc[k][0] * a2.x + acc[k][1] * a2.y + acc[k][2] * a2.z + acc[k][3] * a2.w;
        #pragma unroll
        for (int m = 1; m < 16; m <<= 1) {
            e1 += __shfl_xor(e1, m, 64);
            e2 += __shfl_xor(e2, m, 64);
        }
        // f-reduction leaves group-g's full sum on lane 16*g (within kh=0 half):
        // write from lanes 0 (rows 0..3) and 16 (rows 4..7).
        // R3 BUG was (lane&31)==0 -> lanes {0,32}, both g=0; rows 4..7 never written.
        if ((lane & 15) == 0 && kh == 0) {
            int r = n0 + 4 * g + k;
            ei_t[(size_t)bh * N + r] = e1;
            ej_t[(size_t)bh * N + r] = e2;
        }
    }
}

// ---------------------------------------------------------------------------
// Kernel B: fused scores+softmax+PV. Block = (bh, 16 i-rows); the 4 waves
// each own a j-QUARTER (scores computed exactly once), each doing all 4
// f-tile MFMAs against the shared A-fragment. Partial PV accs + row sums
// combined across waves through a 17KB LDS buffer, normalized, written.
// ---------------------------------------------------------------------------
__global__ __launch_bounds__(256) void gat_attn(
    const unsigned short* __restrict__ hpT, // (B,H,64,N) bf16
    const float* __restrict__ ei_t,         // (B,H,N)
    const float* __restrict__ ej_t,         // (B,H,N)
    const float* __restrict__ mb,           // (N,N) masked bias
    float* __restrict__ out)                // (B,N,H*FOUT)
{
    __shared__ float accs[4][16][66];       // [wave][row][f] +2 pad
    __shared__ float psw[4][16];
    const int t    = threadIdx.x;
    const int blk  = blockIdx.x;            // 32 bh x 64 itiles
    const int bh   = blk >> 6;
    const int i0   = (blk & 63) * 16;
    const int w    = t >> 6;                // j-quarter
    const int lane = t & 63;
    const int li   = lane & 15;
    const int kg   = lane >> 4;

    const float  ei0   = ei_t[(size_t)bh * N + i0 + li];
    const float* ejrow = ej_t + (size_t)bh * N;
    const float* mbrow = mb + (size_t)(i0 + li) * N;
    const unsigned short* bp = hpT + ((size_t)bh * 64 + li) * N;

    f32x4 c0 = {0.f,0.f,0.f,0.f}, c1 = {0.f,0.f,0.f,0.f};
    f32x4 c2 = {0.f,0.f,0.f,0.f}, c3 = {0.f,0.f,0.f,0.f};
    float ps = 0.f;

    const int jbase = w * 256;
    for (int j0 = 0; j0 < 256; j0 += 32) {
        const int jb = jbase + j0 + 8 * kg;
        float4 ejA = *reinterpret_cast<const float4*>(ejrow + jb);
        float4 ejB = *reinterpret_cast<const float4*>(ejrow + jb + 4);
        float4 mA  = *reinterpret_cast<const float4*>(mbrow + jb);
        float4 mB  = *reinterpret_cast<const float4*>(mbrow + jb + 4);
        short8 bf0 = *reinterpret_cast<const short8*>(bp + 0 * 16 * N + jb);
        short8 bf1 = *reinterpret_cast<const short8*>(bp + 1 * 16 * N + jb);
        short8 bf2 = *reinterpret_cast<const short8*>(bp + 2 * 16 * N + jb);
        short8 bf3 = *reinterpret_cast<const short8*>(bp + 3 * 16 * N + jb);

        short8 a0;
        #define SC(EJ, MB, IDX) {                          \
            float e_ = ei0 + (EJ);                         \
            e_ = fmaxf(e_, 0.2f * e_) + (MB);              \
            float p_ = __expf(e_);                         \
            ps += p_;                                      \
            a0[IDX] = (short)f2bf(p_); }
        SC(ejA.x, mA.x, 0)
        SC(ejA.y, mA.y, 1)
        SC(ejA.z, mA.z, 2)
        SC(ejA.w, mA.w, 3)
        SC(ejB.x, mB.x, 4)
        SC(ejB.y, mB.y, 5)
        SC(ejB.z, mB.z, 6)
        SC(ejB.w, mB.w, 7)
        #undef SC

        c0 = __builtin_amdgcn_mfma_f32_16x16x32_bf16(a0, bf0, c0, 0, 0, 0);
        c1 = __builtin_amdgcn_mfma_f32_16x16x32_bf16(a0, bf1, c1, 0, 0, 0);
        c2 = __builtin_amdgcn_mfma_f32_16x16x32_bf16(a0, bf2, c2, 0, 0, 0);
        c3 = __builtin_amdgcn_mfma_f32_16x16x32_bf16(a0, bf3, c3, 0, 0, 0);
    }

    // partial row sums: reduce over the 4 k-groups (rows live on li lanes)
    ps += __shfl_xor(ps, 16, 64);
    ps += __shfl_xor(ps, 32, 64);

    // dump partial accs: C layout col=l&15 (=f within tile), row=4*kg+r
    #pragma unroll
    for (int r = 0; r < 4; ++r) {
        int row = 4 * kg + r;
        accs[w][row][0 * 16 + li] = c0[r];
        accs[w][row][1 * 16 + li] = c1[r];
        accs[w][row][2 * 16 + li] = c2[r];
        accs[w][row][3 * 16 + li] = c3[r];
    }
    if (kg == 0) psw[w][li] = ps;
    __syncthreads();

    // combine 4 j-quarters, normalize, store. 256 threads = 4 rows x 64 f.
    const int f  = t & 63;
    const int rr = t >> 6;
    const int b  = bh >> 2;
    const int hd = bh & 3;
    #pragma unroll
    for (int p = 0; p < 4; ++p) {
        int row = p * 4 + rr;
        float s = (psw[0][row] + psw[1][row]) + (psw[2][row] + psw[3][row]);
        float v = (accs[0][row][f] + accs[1][row][f]) +
                  (accs[2][row][f] + accs[3][row][f]);
        out[(((size_t)b * N + i0 + row) * H + hd) * 64 + f] = v / s;
    }
}

extern "C" void kernel_launch(void* const* d_in, const int* in_sizes, int n_in,
                              void* d_out, int out_size, void* d_ws, size_t ws_size,
                              hipStream_t stream) {
    const float* h    = (const float*)d_in[0];
    const int*   adj  = (const int*)  d_in[1];
    const float* bias = (const float*)d_in[2];
    const float* W    = (const float*)d_in[3];
    const float* a    = (const float*)d_in[4];
    float* out = (float*)d_out;

    char* ws = (char*)d_ws;
    unsigned short* hpT = (unsigned short*)ws;                       // 4 MB
    float* mb   = (float*)(ws + (size_t)B * H * 64 * N * 2);         // 4 MB
    float* ei_t = (float*)(ws + (size_t)B * H * 64 * N * 2 + (size_t)N * N * 4);
    float* ej_t = ei_t + (size_t)B * H * N;

    mb_prep<<<N * N / 4 / 256, 256, 0, stream>>>(adj, bias, mb);
    gat_prep<<<B * N / 8, 256, 0, stream>>>(h, W, a, hpT, ei_t, ej_t);
    gat_attn<<<B * H * (N / 16), 256, 0, stream>>>(hpT, ei_t, ej_t, mb, out);
}

// Round 5
// 72.851 us; speedup vs baseline: 4.6320x; 1.0174x over previous
//
#include <hip/hip_runtime.h>

constexpr int B = 8, N = 1024, FIN = 128, FOUT = 64, H = 4;
constexpr float LOG2E = 1.44269504f;

typedef __attribute__((ext_vector_type(8))) short short8;
typedef __attribute__((ext_vector_type(4))) short short4v;
typedef __attribute__((ext_vector_type(4))) float f32x4;

// f32 -> bf16 round-to-nearest-even (prep-kernel use only)
static __device__ inline unsigned short f2bf(float x) {
    union { float f; unsigned u; } v; v.f = x;
    unsigned r = v.u + 0x7fff + ((v.u >> 16) & 1);
    return (unsigned short)(r >> 16);
}

// ---------------------------------------------------------------------------
// mb[i][j] = adj ? LOG2E*bias : -1e35   (exp2(-1e35)=0; scores prescaled by
// log2e so gat_attn's exp is a single v_exp_f32)
// ---------------------------------------------------------------------------
__global__ __launch_bounds__(256) void mb_prep(
    const int* __restrict__ adj, const float* __restrict__ bias,
    float* __restrict__ mb)
{
    int idx = blockIdx.x * 256 + threadIdx.x;   // over N*N/4
    int4   a4 = reinterpret_cast<const int4*>(adj)[idx];
    float4 b4 = reinterpret_cast<const float4*>(bias)[idx];
    float4 o;
    o.x = a4.x ? LOG2E * b4.x : -1e35f;
    o.y = a4.y ? LOG2E * b4.y : -1e35f;
    o.z = a4.z ? LOG2E * b4.z : -1e35f;
    o.w = a4.w ? LOG2E * b4.w : -1e35f;
    reinterpret_cast<float4*>(mb)[idx] = o;
}

// ---------------------------------------------------------------------------
// Kernel A: h_prime GEMM + ei/ej (prescaled by LOG2E). Block = 8 rows; wave =
// head; lanes split K in halves (kh=lane>>5), combined via shfl_xor(32).
// hpT (B,H,64,N) bf16 f-major.
// ---------------------------------------------------------------------------
__global__ __launch_bounds__(256) void gat_prep(
    const float* __restrict__ h,      // (B,N,FIN)
    const float* __restrict__ W,      // (H,FIN,FOUT)
    const float* __restrict__ a,      // (H,2*FOUT,1)
    unsigned short* __restrict__ hpT, // (B,H,64,N) bf16
    float* __restrict__ ei_t,         // (B,H,N) *LOG2E
    float* __restrict__ ej_t)         // (B,H,N) *LOG2E
{
    __shared__ float h_lds[8][132];
    const int t   = threadIdx.x;
    const int blk = blockIdx.x;
    const int b   = blk >> 7;
    const int n0  = (blk & 127) * 8;

    {
        const float* src = h + ((size_t)b * N + n0) * FIN;
        float4 x = reinterpret_cast<const float4*>(src)[t];
        int fl = t * 4;
        *reinterpret_cast<float4*>(&h_lds[fl >> 7][fl & 127]) = x;
    }
    __syncthreads();

    const int hd   = t >> 6;
    const int lane = t & 63;
    const int f0   = (lane & 15) * 4;
    const int g    = (lane >> 4) & 1;
    const int kh   = lane >> 5;

    float acc[4][4];
    #pragma unroll
    for (int k = 0; k < 4; ++k)
        #pragma unroll
        for (int j = 0; j < 4; ++j) acc[k][j] = 0.f;

    const float* Wp = W + (size_t)hd * FIN * FOUT + (size_t)kh * 64 * FOUT + f0;
    #pragma unroll 4
    for (int i = 0; i < 64; ++i) {
        float4 w4 = *reinterpret_cast<const float4*>(Wp + (size_t)i * FOUT);
        #pragma unroll
        for (int k = 0; k < 4; ++k) {
            float hv = h_lds[4 * g + k][kh * 64 + i];
            acc[k][0] = fmaf(hv, w4.x, acc[k][0]);
            acc[k][1] = fmaf(hv, w4.y, acc[k][1]);
            acc[k][2] = fmaf(hv, w4.z, acc[k][2]);
            acc[k][3] = fmaf(hv, w4.w, acc[k][3]);
        }
    }

    #pragma unroll
    for (int k = 0; k < 4; ++k)
        #pragma unroll
        for (int j = 0; j < 4; ++j)
            acc[k][j] += __shfl_xor(acc[k][j], 32, 64);

    const int bh = b * H + hd;
    if (kh == 0) {
        #pragma unroll
        for (int jj = 0; jj < 4; ++jj) {
            short4v v4;
            v4[0] = (short)f2bf(acc[0][jj]);
            v4[1] = (short)f2bf(acc[1][jj]);
            v4[2] = (short)f2bf(acc[2][jj]);
            v4[3] = (short)f2bf(acc[3][jj]);
            *reinterpret_cast<short4v*>(
                hpT + ((size_t)bh * 64 + f0 + jj) * N + n0 + 4 * g) = v4;
        }
    }

    float4 a1 = *reinterpret_cast<const float4*>(a + (size_t)hd * 2 * FOUT + f0);
    float4 a2 = *reinterpret_cast<const float4*>(a + (size_t)hd * 2 * FOUT + FOUT + f0);
    #pragma unroll
    for (int k = 0; k < 4; ++k) {
        float e1 = acc[k][0] * a1.x + acc[k][1] * a1.y + acc[k][2] * a1.z + acc[k][3] * a1.w;
        float e2 = acc[k][0] * a2.x + acc[k][1] * a2.y + acc[k][2] * a2.z + acc[k][3] * a2.w;
        #pragma unroll
        for (int m = 1; m < 16; m <<= 1) {
            e1 += __shfl_xor(e1, m, 64);
            e2 += __shfl_xor(e2, m, 64);
        }
        // group-g's full sum sits on lane 16*g of the kh=0 half
        if ((lane & 15) == 0 && kh == 0) {
            int r = n0 + 4 * g + k;
            ei_t[(size_t)bh * N + r] = LOG2E * e1;
            ej_t[(size_t)bh * N + r] = LOG2E * e2;
        }
    }
}

// ---------------------------------------------------------------------------
// Kernel B: fused scores+softmax+PV. Block = (bh, 16 i-rows); 4 waves own
// j-quarters (scores computed once). Depth-1 prefetch: while chunk k's scores
// + 5 MFMAs (4 f-tiles + all-ones row-sum tile) run, chunk k+1's mb/bf loads
// are in flight. exp is a single v_exp_f32 (inputs prescaled by log2e);
// p->bf16 packing via v_cvt_pk_bf16_f32.
// ---------------------------------------------------------------------------
__global__ __launch_bounds__(256) void gat_attn(
    const unsigned short* __restrict__ hpT, // (B,H,64,N) bf16
    const float* __restrict__ ei_t,         // (B,H,N) *LOG2E
    const float* __restrict__ ej_t,         // (B,H,N) *LOG2E
    const float* __restrict__ mb,           // (N,N) masked bias *LOG2E
    float* __restrict__ out)                // (B,N,H*FOUT)
{
    __shared__ float accs[4][16][66];
    __shared__ float psw[4][16];
    const int t    = threadIdx.x;
    const int blk  = blockIdx.x;
    const int bh   = blk >> 6;
    const int i0   = (blk & 63) * 16;
    const int w    = t >> 6;
    const int lane = t & 63;
    const int li   = lane & 15;
    const int kg   = lane >> 4;

    const float  ei0   = ei_t[(size_t)bh * N + i0 + li];
    const float* ejrow = ej_t + (size_t)bh * N;
    const float* mbrow = mb + (size_t)(i0 + li) * N;
    const unsigned short* bp = hpT + ((size_t)bh * 64 + li) * N;

    f32x4 c0 = {0.f,0.f,0.f,0.f}, c1 = {0.f,0.f,0.f,0.f};
    f32x4 c2 = {0.f,0.f,0.f,0.f}, c3 = {0.f,0.f,0.f,0.f};
    f32x4 c4 = {0.f,0.f,0.f,0.f};
    const short obf = (short)0x3F80;                      // bf16 1.0
    const short8 ones = {obf,obf,obf,obf,obf,obf,obf,obf};

    const int jb = w * 256 + 8 * kg;

    float4 mA0, mB0, mA1, mB1;
    short8 b00, b01, b02, b03, b10, b11, b12, b13;

    #define LOADSET(MA, MB, B0, B1, B2, B3, OFS) {                       \
        MA = *reinterpret_cast<const float4*>(mbrow + (OFS));            \
        MB = *reinterpret_cast<const float4*>(mbrow + (OFS) + 4);        \
        B0 = *reinterpret_cast<const short8*>(bp + 0 * 16 * N + (OFS));  \
        B1 = *reinterpret_cast<const short8*>(bp + 1 * 16 * N + (OFS));  \
        B2 = *reinterpret_cast<const short8*>(bp + 2 * 16 * N + (OFS));  \
        B3 = *reinterpret_cast<const short8*>(bp + 3 * 16 * N + (OFS)); }

    #define SCORE(PD, EJ, MBV) {                                         \
        float e_ = ei0 + (EJ);                                           \
        e_ = fmaxf(e_, 0.2f * e_) + (MBV);                               \
        asm("v_exp_f32 %0, %1" : "=v"(PD) : "v"(e_)); }

    #define COMPSET(MA, MB, B0, B1, B2, B3, OFS) {                       \
        float4 ejA = *reinterpret_cast<const float4*>(ejrow + (OFS));    \
        float4 ejB = *reinterpret_cast<const float4*>(ejrow + (OFS) + 4);\
        float p0,p1,p2,p3,p4,p5,p6,p7;                                   \
        SCORE(p0, ejA.x, MA.x) SCORE(p1, ejA.y, MA.y)                    \
        SCORE(p2, ejA.z, MA.z) SCORE(p3, ejA.w, MA.w)                    \
        SCORE(p4, ejB.x, MB.x) SCORE(p5, ejB.y, MB.y)                    \
        SCORE(p6, ejB.z, MB.z) SCORE(p7, ejB.w, MB.w)                    \
        int4 pk_;                                                        \
        asm("v_cvt_pk_bf16_f32 %0, %1, %2" : "=v"(pk_.x) : "v"(p0), "v"(p1)); \
        asm("v_cvt_pk_bf16_f32 %0, %1, %2" : "=v"(pk_.y) : "v"(p2), "v"(p3)); \
        asm("v_cvt_pk_bf16_f32 %0, %1, %2" : "=v"(pk_.z) : "v"(p4), "v"(p5)); \
        asm("v_cvt_pk_bf16_f32 %0, %1, %2" : "=v"(pk_.w) : "v"(p6), "v"(p7)); \
        short8 a0_ = *reinterpret_cast<short8*>(&pk_);                   \
        c0 = __builtin_amdgcn_mfma_f32_16x16x32_bf16(a0_, B0, c0, 0, 0, 0); \
        c1 = __builtin_amdgcn_mfma_f32_16x16x32_bf16(a0_, B1, c1, 0, 0, 0); \
        c2 = __builtin_amdgcn_mfma_f32_16x16x32_bf16(a0_, B2, c2, 0, 0, 0); \
        c3 = __builtin_amdgcn_mfma_f32_16x16x32_bf16(a0_, B3, c3, 0, 0, 0); \
        c4 = __builtin_amdgcn_mfma_f32_16x16x32_bf16(a0_, ones, c4, 0, 0, 0); }

    LOADSET(mA0, mB0, b00, b01, b02, b03, jb)
    #pragma unroll
    for (int jj = 0; jj < 4; ++jj) {
        LOADSET(mA1, mB1, b10, b11, b12, b13, jb + 64 * jj + 32)
        COMPSET(mA0, mB0, b00, b01, b02, b03, jb + 64 * jj)
        if (jj < 3) LOADSET(mA0, mB0, b00, b01, b02, b03, jb + 64 * jj + 64)
        COMPSET(mA1, mB1, b10, b11, b12, b13, jb + 64 * jj + 32)
    }
    #undef LOADSET
    #undef SCORE
    #undef COMPSET

    // dump partial accs: C layout col=l&15 (=f within tile), row=4*kg+r
    #pragma unroll
    for (int r = 0; r < 4; ++r) {
        int row = 4 * kg + r;
        accs[w][row][0 * 16 + li] = c0[r];
        accs[w][row][1 * 16 + li] = c1[r];
        accs[w][row][2 * 16 + li] = c2[r];
        accs[w][row][3 * 16 + li] = c3[r];
    }
    if (li == 0) {
        #pragma unroll
        for (int r = 0; r < 4; ++r) psw[w][4 * kg + r] = c4[r];
    }
    __syncthreads();

    // combine 4 j-quarters, normalize, store. 256 threads = 4 rows x 64 f.
    const int f  = t & 63;
    const int rr = t >> 6;
    const int b  = bh >> 2;
    const int hd = bh & 3;
    #pragma unroll
    for (int p = 0; p < 4; ++p) {
        int row = p * 4 + rr;
        float s = (psw[0][row] + psw[1][row]) + (psw[2][row] + psw[3][row]);
        float v = (accs[0][row][f] + accs[1][row][f]) +
                  (accs[2][row][f] + accs[3][row][f]);
        out[(((size_t)b * N + i0 + row) * H + hd) * 64 + f] = v / s;
    }
}

extern "C" void kernel_launch(void* const* d_in, const int* in_sizes, int n_in,
                              void* d_out, int out_size, void* d_ws, size_t ws_size,
                              hipStream_t stream) {
    const float* h    = (const float*)d_in[0];
    const int*   adj  = (const int*)  d_in[1];
    const float* bias = (const float*)d_in[2];
    const float* W    = (const float*)d_in[3];
    const float* a    = (const float*)d_in[4];
    float* out = (float*)d_out;

    char* ws = (char*)d_ws;
    unsigned short* hpT = (unsigned short*)ws;                       // 4 MB
    float* mb   = (float*)(ws + (size_t)B * H * 64 * N * 2);         // 4 MB
    float* ei_t = (float*)(ws + (size_t)B * H * 64 * N * 2 + (size_t)N * N * 4);
    float* ej_t = ei_t + (size_t)B * H * N;

    mb_prep<<<N * N / 4 / 256, 256, 0, stream>>>(adj, bias, mb);
    gat_prep<<<B * N / 8, 256, 0, stream>>>(h, W, a, hpT, ei_t, ej_t);
    gat_attn<<<B * H * (N / 16), 256, 0, stream>>>(hpT, ei_t, ej_t, mb, out);
}